// Round 1
// baseline (98.473 us; speedup 1.0000x reference)
//
#include <hip/hip_runtime.h>
#include <math.h>

// Problem constants (from reference): N_PTS=1e6, K_DIM=3, N_BINS=21
// wv_tilde row = 43 floats: v_tilde[22] then w_tilde[21]
#define NROWS        3000000     // N_PTS * K_DIM
#define ROWS_PER_BLK 192         // 3 waves, 64 points per block
#define NBINS        21
#define NV           22
#define DROW         43          // floats per row
#define FLOATS_PER_BLK (ROWS_PER_BLK * DROW)   // 8256
#define F4_PER_BLK     (FLOATS_PER_BLK / 4)    // 2064

__global__ __launch_bounds__(ROWS_PER_BLK) void pwquad_kernel(
    const float* __restrict__ y,
    const float* __restrict__ wv,
    float* __restrict__ out)
{
    __shared__ float lds[FLOATS_PER_BLK];   // 33024 B, exact copy of chunk
    __shared__ float lt[ROWS_PER_BLK];      // per-row log terms

    const int tid = threadIdx.x;
    const int blk = blockIdx.x;

    // ---- Stage 192 rows (contiguous 33 KB) into LDS, coalesced float4 ----
    const float4* __restrict__ src4 =
        reinterpret_cast<const float4*>(wv + (long long)blk * FLOATS_PER_BLK);
    float4* l4 = reinterpret_cast<float4*>(lds);

    float4 r[10];
#pragma unroll
    for (int it = 0; it < 10; ++it) r[it] = src4[tid + it * ROWS_PER_BLK];
    const bool tail = (tid < (F4_PER_BLK - 10 * ROWS_PER_BLK));  // tid < 144
    float4 rt;
    if (tail) rt = src4[tid + 10 * ROWS_PER_BLK];
#pragma unroll
    for (int it = 0; it < 10; ++it) l4[tid + it * ROWS_PER_BLK] = r[it];
    if (tail) l4[tid + 10 * ROWS_PER_BLK] = rt;
    __syncthreads();

    // ---- Per-row computation ----
    const int row = blk * ROWS_PER_BLK + tid;
    const float yv = y[row];
    const float* myrow = lds + tid * DROW;   // stride 43 (odd) -> conflict-free

    const float EPSF = 1.1920929e-07f;   // np.finfo(float32).eps

    // w = exp(w_tilde); normalize by sum
    float w[NBINS];
    float wnorm = 0.f;
#pragma unroll
    for (int j = 0; j < NBINS; ++j) { w[j] = __expf(myrow[NV + j]); wnorm += w[j]; }
    const float invw = 1.0f / wnorm;
#pragma unroll
    for (int j = 0; j < NBINS; ++j) w[j] *= invw;

    // ve = exp(v_tilde); trapezoid normalization
    float v[NV];
#pragma unroll
    for (int i = 0; i < NV; ++i) v[i] = __expf(myrow[i]);
    float T = 0.f;
#pragma unroll
    for (int j = 0; j < NBINS; ++j) T += (v[j] + v[j + 1]) * 0.5f * w[j];
    const float invT = 1.0f / T;
#pragma unroll
    for (int i = 0; i < NV; ++i) v[i] = fmaxf(v[i] * invT, 1e-6f);

    // ---- Edge search: vw_k = prefix sums of (v[j]+v[j+1])/2 * w[j] (non-decreasing)
    // edge = min(last k with vw_k <= y, 20). Latch state while condition holds.
    float vw = 0.f, wsum = 0.f;
    float vwe = 0.f, wse = 0.f;            // vw[edge], wsum_shift[edge]
    float v0 = v[0], v1 = v[1], we = w[0]; // edge = 0 defaults
#pragma unroll
    for (int j = 0; j < 20; ++j) {         // covers k = 1..20 (k=21 clips to 20)
        const float inc = (v[j] + v[j + 1]) * 0.5f * w[j];
        vw += inc;
        wsum += w[j];
        const bool q = (vw <= yv);
        vwe = q ? vw       : vwe;
        wse = q ? wsum     : wse;
        v0  = q ? v[j + 1] : v0;
        v1  = q ? v[j + 2] : v1;
        we  = q ? w[j + 1] : we;
    }

    // ---- Quadratic solve within the bin ----
    float a = (v1 - v0) * we;
    const float bq = v0 * we;
    const float c = vwe - yv;
    a = (fabsf(a) < EPSF) ? EPSF : a;
    const float dd = fmaxf(bq * bq - 2.0f * a * c, 0.f);
    const float sq = sqrtf(dd);
    const float sol1 = (-bq - sq) / a;
    const float sol2 = (-bq + sq) / a;
    float sol = (sol1 >= 0.f && sol1 < 1.f) ? sol1 : sol2;
    sol = fminf(fmaxf(sol, EPSF), 1.f - EPSF);
    float x = we * sol + wse;
    x = fminf(fmaxf(x, EPSF), 1.f - EPSF);
    out[row] = x;

    // ---- logj: sum of 3 per-dim terms per point ----
    lt[tid] = __logf(v0 + (v1 - v0) * sol);
    __syncthreads();
    if (tid % 3 == 0) {
        out[NROWS + blk * (ROWS_PER_BLK / 3) + tid / 3] =
            -(lt[tid] + lt[tid + 1] + lt[tid + 2]);
    }
}

extern "C" void kernel_launch(void* const* d_in, const int* in_sizes, int n_in,
                              void* d_out, int out_size, void* d_ws, size_t ws_size,
                              hipStream_t stream) {
    const float* y  = (const float*)d_in[0];
    const float* wv = (const float*)d_in[1];
    float* out = (float*)d_out;

    const int nblocks = NROWS / ROWS_PER_BLK;   // 15625 exactly
    pwquad_kernel<<<nblocks, ROWS_PER_BLK, 0, stream>>>(y, wv, out);
}